// Round 9
// baseline (153.337 us; speedup 1.0000x reference)
//
#include <hip/hip_runtime.h>

typedef __attribute__((ext_vector_type(8))) short short8;   // 8 bf16 = 4 VGPRs
typedef __attribute__((ext_vector_type(4))) float floatx4;  // MFMA acc

typedef __attribute__((address_space(3))) unsigned int lds_u32;
typedef __attribute__((address_space(1))) const unsigned int glb_u32;

static __device__ __forceinline__ unsigned short f2bf(float f) {
    unsigned int u = __float_as_uint(f);
    return (unsigned short)((u + 0x7FFFu + ((u >> 16) & 1u)) >> 16);   // RNE
}
// async 16-B global->LDS DMA; LDS dest = wave-uniform base + lane*16
static __device__ __forceinline__ void cp16(const ushort* g, ushort* l) {
    __builtin_amdgcn_global_load_lds((glb_u32*)g, (lds_u32*)l, 16, 0, 0);
}

// ---- prep: x->bf16 padded [B][514][256]; w[F][C][3] -> swizzled [12][256][64] ----
// (identical layouts to R4/R8 - proven correct)
__global__ __launch_bounds__(256)
void prep_kernel(const float* __restrict__ x, const float* __restrict__ w1,
                 const float* __restrict__ w2,
                 ushort* __restrict__ xb, ushort* __restrict__ h1b,
                 ushort* __restrict__ w1pb, ushort* __restrict__ w2pb)
{
    const int blk = blockIdx.x, tid = threadIdx.x;
    if (blk < 4112) {
        const int r = blk * 4 + (tid >> 6);
        const int c = (tid & 63) * 4;
        const int b = r / 514, tp = r % 514;
        ushort4 o;
        if (tp >= 1 && tp <= 512) {
            float4 v = *(const float4*)(x + ((size_t)(b * 512 + tp - 1) * 256 + c));
            o.x = f2bf(v.x); o.y = f2bf(v.y); o.z = f2bf(v.z); o.w = f2bf(v.w);
        } else {
            o.x = o.y = o.z = o.w = 0;
            *(ushort4*)(h1b + (size_t)r * 256 + c) = o;   // zero h1b pad rows
        }
        *(ushort4*)(xb + (size_t)r * 256 + c) = o;
    } else {
        const bool second = blk >= 4880;
        const int e = (blk - (second ? 4880 : 4112)) * 256 + tid;
        const float* w = second ? w2 : w1;
        ushort* wpb = second ? w2pb : w1pb;
        const int f = e / 768, j = e % 768;
        const int c = j & 255, kr = j >> 8;
        const int s = j >> 6, kk = j & 63;
        wpb[s * 16384 + f * 64 + (((kk >> 3) ^ (f & 7)) << 3) + (kk & 7)]
            = f2bf(w[f * 768 + c * 3 + kr]);
    }
}

// ---- conv1d(K=3) MFMA GEMM: M=64 tiles (HALVED B staging) + true dbuf pipeline ----
// Grid: 256 conv blocks (+576 gather when IS_CONV2). Block 512 thr (8 waves, 2/SIMD).
// Tile 64 rows x 256 cols; K=768 in 12 steps of BK=64. Stage = A(8KB)+B(32KB) per
// step, double-buffered (80 KB LDS). Pipeline per step: raw s_barrier (WAR) ->
// issue step s+1 DMAs -> s_waitcnt vmcnt(5) (own step-s batch only) -> raw
// s_barrier -> ds_read frags + 16 MFMA/wave. No full vmcnt(0) drain mid-loop.
template<bool IS_CONV2>
__global__ __launch_bounds__(512, 2)
void conv_mfma_kernel(const ushort* __restrict__ xb,   // [B][514][256] bf16 padded
                      const ushort* __restrict__ wpb,  // [12][256][64] bf16 swizzled
                      const float* __restrict__ cbias,
                      const float* __restrict__ gamma, const float* __restrict__ beta,
                      const float* __restrict__ lw, const float* __restrict__ lb,
                      ushort* __restrict__ outb,       // conv1: h1b
                      float* __restrict__ durp,        // conv2: [B][512]
                      const float* __restrict__ x,     // conv2 gather path
                      const int* __restrict__ target,
                      float* __restrict__ out0)        // [B][2304][256]
{
    __shared__ ushort stage[2][20480];   // 80 KB: [buf][A 4096 sh | B 16384 sh]
    __shared__ float sum_s[4][64], sq_s[4][64], mu_s[64], rs_s[64];
    __shared__ int cum[512], sidx[128];  // gather path only

    const int tid = threadIdx.x;

    if (IS_CONV2 && blockIdx.x >= 256) {
        // ---------- gather: 576 blocks x 128 output rows (512 thr) ----------
        const int g = blockIdx.x - 256;
        const int b = g / 18, seg = g % 18;
        cum[tid] = target[b * 512 + tid];
        __syncthreads();
        for (int off = 1; off < 512; off <<= 1) {
            int v = (tid >= off) ? cum[tid - off] : 0;
            __syncthreads();
            cum[tid] += v;
            __syncthreads();
        }
        const int total = cum[511];
        if (tid < 128) {
            int t = seg * 128 + tid;
            int lo = 0, hi = 512;
            while (lo < hi) {
                int mid = (lo + hi) >> 1;
                if (cum[mid] <= t) lo = mid + 1; else hi = mid;
            }
            sidx[tid] = (t < total) ? ((lo < 512) ? lo : 511) : -1;
        }
        __syncthreads();
        const float4* x4 = (const float4*)x;
        float4* o4 = (float4*)out0;
        const int lane6 = tid & 63, g8 = tid >> 6;
        #pragma unroll 4
        for (int it = 0; it < 16; ++it) {
            int r = it * 8 + g8;
            int idx = sidx[r];
            float4 v = make_float4(0.f, 0.f, 0.f, 0.f);
            if (idx >= 0) v = x4[((size_t)(b * 512 + idx)) * 64 + lane6];
            o4[((size_t)(b * 2304 + seg * 128 + r)) * 64 + lane6] = v;
        }
        return;
    }

    // ---------- conv path ----------
    const int w_ = tid >> 6, lane = tid & 63;
    const int q = lane >> 4, col = lane & 15;
    const int rg = w_ >> 2, colw = w_ & 3;          // wave = 32 rows x 64 cols
    const int b  = blockIdx.x >> 3;
    const int t0 = (blockIdx.x & 7) << 6;

    const ushort* inb = xb + (size_t)b * 514 * 256;
    const int arow = tid >> 3;                      // A-stage: row 0..63
    const int ajs  = (tid & 7) ^ (arow & 7);        // source-quad swizzle

    floatx4 acc[2][4] = {};

    // ---- stage helper (inlined twice): 1 A-cp16 + 4 B-cp16 per thread ----
#define STAGE_STEP(S, BUF)                                                       \
    {                                                                            \
        const int krow = (S) >> 2, cb = ((S) & 3) << 6;                          \
        cp16(inb + (size_t)(t0 + krow + arow) * 256 + cb + ajs * 8,              \
             (BUF) + w_ * 512);                                                  \
        const ushort* wsrc = wpb + (size_t)(S) * 16384;                          \
        _Pragma("unroll")                                                        \
        for (int i = 0; i < 4; ++i)                                              \
            cp16(wsrc + (i * 512 + tid) * 8,                                     \
                 (BUF) + 4096 + i * 4096 + w_ * 512);                            \
    }

    STAGE_STEP(0, stage[0])                          // prologue

    for (int s = 0; s < 12; ++s) {
        __builtin_amdgcn_s_barrier();                // WAR: all done reading buf[(s+1)&1]
        if (s < 11) {
            STAGE_STEP(s + 1, stage[(s + 1) & 1])
            asm volatile("s_waitcnt vmcnt(5)" ::: "memory");   // own step-s batch done
        } else {
            asm volatile("s_waitcnt vmcnt(0)" ::: "memory");
        }
        __builtin_amdgcn_s_barrier();                // everyone's step-s data landed

        const ushort* At = stage[s & 1];
        const ushort* Bt = stage[s & 1] + 4096;
        short8 af[2][2], bf[4][2];
        #pragma unroll
        for (int mi = 0; mi < 2; ++mi) {
            const int ri = rg * 32 + mi * 16 + col;
            #pragma unroll
            for (int kh = 0; kh < 2; ++kh)
                af[mi][kh] = *(const short8*)((const char*)At
                    + ri * 128 + (((kh * 4 + q) ^ (ri & 7)) * 16));
        }
        #pragma unroll
        for (int ni = 0; ni < 4; ++ni) {
            const int n = colw * 64 + ni * 16 + col;
            #pragma unroll
            for (int kh = 0; kh < 2; ++kh)
                bf[ni][kh] = *(const short8*)((const char*)Bt
                    + n * 128 + (((kh * 4 + q) ^ (n & 7)) * 16));
        }
        #pragma unroll
        for (int kh = 0; kh < 2; ++kh)
            #pragma unroll
            for (int mi = 0; mi < 2; ++mi)
                #pragma unroll
                for (int ni = 0; ni < 4; ++ni)
                    acc[mi][ni] = __builtin_amdgcn_mfma_f32_16x16x32_bf16(
                        af[mi][kh], bf[ni][kh], acc[mi][ni], 0, 0, 0);
    }
#undef STAGE_STEP

    // ---- epilogue: bias + LN stats (64 rows, 4 col-waves per row) ----
    const int bc0 = colw * 64;
    float cb4[4], gm4[4], bt4[4];
    #pragma unroll
    for (int ni = 0; ni < 4; ++ni) {
        cb4[ni] = cbias[bc0 + ni * 16 + col];
        gm4[ni] = gamma[bc0 + ni * 16 + col];
        bt4[ni] = beta [bc0 + ni * 16 + col];
    }
    float rsum[2][4] = {}, rsq[2][4] = {};
    #pragma unroll
    for (int mi = 0; mi < 2; ++mi)
        #pragma unroll
        for (int ni = 0; ni < 4; ++ni)
            #pragma unroll
            for (int r = 0; r < 4; ++r) {
                float v = acc[mi][ni][r] + cb4[ni];
                acc[mi][ni][r] = v;
                rsum[mi][r] += v;
                rsq [mi][r] += v * v;
            }
    #pragma unroll
    for (int mi = 0; mi < 2; ++mi)
        #pragma unroll
        for (int r = 0; r < 4; ++r) {
            float s = rsum[mi][r], ss = rsq[mi][r];
            #pragma unroll
            for (int d = 8; d > 0; d >>= 1) {
                s  += __shfl_down(s,  d, 16);
                ss += __shfl_down(ss, d, 16);
            }
            if (col == 0) {
                const int row = rg * 32 + mi * 16 + q * 4 + r;
                sum_s[colw][row] = s;
                sq_s [colw][row] = ss;
            }
        }
    __syncthreads();
    if (tid < 64) {
        float s  = sum_s[0][tid] + sum_s[1][tid] + sum_s[2][tid] + sum_s[3][tid];
        float ss = sq_s [0][tid] + sq_s [1][tid] + sq_s [2][tid] + sq_s [3][tid];
        float mu = s * (1.f / 256.f);
        mu_s[tid] = mu;
        rs_s[tid] = rsqrtf(ss * (1.f / 256.f) - mu * mu + 1e-5f);
    }
    __syncthreads();

    if (!IS_CONV2) {
        // normalize -> bf16 bounce in LDS -> coalesced 16-B global stores
        ushort* yb = stage[0];                        // 64 rows x 256 sh = 32 KB
        #pragma unroll
        for (int mi = 0; mi < 2; ++mi)
            #pragma unroll
            for (int ni = 0; ni < 4; ++ni)
                #pragma unroll
                for (int r = 0; r < 4; ++r) {
                    const int row = rg * 32 + mi * 16 + q * 4 + r;
                    float v = (acc[mi][ni][r] - mu_s[row]) * rs_s[row] * gm4[ni] + bt4[ni];
                    yb[row * 256 + bc0 + ni * 16 + col] = f2bf(fmaxf(v, 0.f));
                }
        __syncthreads();
        #pragma unroll
        for (int i = 0; i < 4; ++i) {
            const int idx = i * 512 + tid;            // 2048 chunks of 16 B
            const int row = idx >> 5, c = idx & 31;
            *(short8*)(outb + ((size_t)b * 514 + t0 + row + 1) * 256 + c * 8)
                = *(const short8*)(yb + row * 256 + c * 8);
        }
    } else {
        float lw4[4];
        #pragma unroll
        for (int ni = 0; ni < 4; ++ni) lw4[ni] = lw[bc0 + ni * 16 + col];
        float dsum[2][4] = {};
        #pragma unroll
        for (int mi = 0; mi < 2; ++mi)
            #pragma unroll
            for (int ni = 0; ni < 4; ++ni)
                #pragma unroll
                for (int r = 0; r < 4; ++r) {
                    const int row = rg * 32 + mi * 16 + q * 4 + r;
                    float v = (acc[mi][ni][r] - mu_s[row]) * rs_s[row] * gm4[ni] + bt4[ni];
                    dsum[mi][r] += fmaxf(v, 0.f) * lw4[ni];
                }
        #pragma unroll
        for (int mi = 0; mi < 2; ++mi)
            #pragma unroll
            for (int r = 0; r < 4; ++r) {
                float s = dsum[mi][r];
                #pragma unroll
                for (int d = 8; d > 0; d >>= 1) s += __shfl_down(s, d, 16);
                if (col == 0) sum_s[colw][rg * 32 + mi * 16 + q * 4 + r] = s;
            }
        __syncthreads();
        if (tid < 64)
            durp[b * 512 + t0 + tid] = fmaxf(sum_s[0][tid] + sum_s[1][tid]
                                           + sum_s[2][tid] + sum_s[3][tid] + lb[0], 0.f);
    }
}

extern "C" void kernel_launch(void* const* d_in, const int* in_sizes, int n_in,
                              void* d_out, int out_size, void* d_ws, size_t ws_size,
                              hipStream_t stream) {
    const float* x      = (const float*)d_in[0];
    const int*   target = (const int*)  d_in[1];
    const float* c1w = (const float*)d_in[3];
    const float* c1b = (const float*)d_in[4];
    const float* g1  = (const float*)d_in[5];
    const float* b1  = (const float*)d_in[6];
    const float* c2w = (const float*)d_in[7];
    const float* c2b = (const float*)d_in[8];
    const float* g2  = (const float*)d_in[9];
    const float* b2  = (const float*)d_in[10];
    const float* lw  = (const float*)d_in[11];
    const float* lb  = (const float*)d_in[12];

    const size_t PADEL = (size_t)32 * 514 * 256;
    ushort* xb   = (ushort*)d_ws;
    ushort* h1b  = xb + PADEL;
    ushort* w1pb = h1b + PADEL;
    ushort* w2pb = w1pb + 196608;

    float* out0 = (float*)d_out;                  // [32, 2304, 256]
    float* durp = out0 + (size_t)32 * 2304 * 256; // [32, 512]

    prep_kernel<<<5648, 256, 0, stream>>>(x, c1w, c2w, xb, h1b, w1pb, w2pb);
    conv_mfma_kernel<false><<<256, 512, 0, stream>>>(
        xb, w1pb, c1b, g1, b1, nullptr, nullptr, h1b, nullptr,
        nullptr, nullptr, nullptr);
    conv_mfma_kernel<true><<<256 + 576, 512, 0, stream>>>(
        h1b, w2pb, c2b, g2, b2, lw, lb, nullptr, durp,
        x, target, out0);
}